// Round 6
// baseline (1594.531 us; speedup 1.0000x reference)
//
#include <hip/hip_runtime.h>

#define N_NODES 50000
#define N_EDGES 800000
#define D       128
#define THREADS 256
#define EPS     1e-5f
#define SCAN_B  196     // ceil(N_NODES/256)
#define MTILES  3125    // N_NODES / 16

typedef __attribute__((ext_vector_type(8))) __bf16  bf16x8;
typedef __attribute__((ext_vector_type(8))) short   short8;
typedef __attribute__((ext_vector_type(4))) float   f32x4;
typedef __attribute__((ext_vector_type(4))) unsigned int u32x4;

// pack fp32 -> (bf16_hi << 16) | bf16_lo  (bf16x2 split: hi+lo ~= x to ~2^-17 rel)
__device__ inline unsigned int packbf(float x) {
    unsigned int u  = __float_as_uint(x);
    unsigned int hi = (u + 0x7FFFu + ((u >> 16) & 1u)) >> 16;
    float hf = __uint_as_float(hi << 16);
    float lo = x - hf;
    unsigned int ul  = __float_as_uint(lo);
    unsigned int l16 = (ul + 0x7FFFu + ((ul >> 16) & 1u)) >> 16;
    return (hi << 16) | (l16 & 0xFFFFu);
}
__device__ inline float unpackbf(unsigned int u) {
    return __uint_as_float(u & 0xFFFF0000u) + __uint_as_float(u << 16);
}

// ---------------- CSR build ----------------

__global__ void count_kernel(const int* __restrict__ dst, int* __restrict__ deg) {
    int e = blockIdx.x * 256 + threadIdx.x;
    if (e < N_EDGES) atomicAdd(&deg[dst[e]], 1);
}

__global__ void block_reduce_kernel(const int* __restrict__ deg, int* __restrict__ bsum) {
    __shared__ int red[256];
    int i = blockIdx.x * 256 + threadIdx.x;
    red[threadIdx.x] = (i < N_NODES) ? deg[i] : 0;
    __syncthreads();
    for (int off = 128; off > 0; off >>= 1) {
        if (threadIdx.x < off) red[threadIdx.x] += red[threadIdx.x + off];
        __syncthreads();
    }
    if (threadIdx.x == 0) bsum[blockIdx.x] = red[0];
}

__global__ void block_scan_kernel(const int* __restrict__ bsum, int* __restrict__ bbase) {
    __shared__ int s[256];
    const int t = threadIdx.x;
    const int v = (t < SCAN_B) ? bsum[t] : 0;
    s[t] = v;
    __syncthreads();
    for (int off = 1; off < 256; off <<= 1) {
        int add = (t >= off) ? s[t - off] : 0;
        __syncthreads();
        s[t] += add;
        __syncthreads();
    }
    if (t < SCAN_B) bbase[t] = s[t] - v;   // exclusive
}

__global__ void expand_kernel(const int* __restrict__ deg, const int* __restrict__ bbase,
                              int* __restrict__ row_start, int* __restrict__ cursor) {
    __shared__ int s[256];
    const int t = threadIdx.x;
    const int i = blockIdx.x * 256 + t;
    const int v = (i < N_NODES) ? deg[i] : 0;
    s[t] = v;
    __syncthreads();
    for (int off = 1; off < 256; off <<= 1) {
        int add = (t >= off) ? s[t - off] : 0;
        __syncthreads();
        s[t] += add;
        __syncthreads();
    }
    const int excl = bbase[blockIdx.x] + s[t] - v;
    if (i < N_NODES) { row_start[i] = excl; cursor[i] = excl; }
    if (i == N_NODES - 1) row_start[N_NODES] = excl + v;
}

__global__ void fill_kernel(const int* __restrict__ src, const int* __restrict__ dst,
                            int* __restrict__ cursor, int* __restrict__ ssrc) {
    int e = blockIdx.x * 256 + threadIdx.x;
    if (e < N_EDGES) {
        int d = dst[e];
        int p = atomicAdd(&cursor[d], 1);
        ssrc[p] = src[e];
    }
}

// ---------------- prep: weights + layer-0 h into packed/bf16 form ----------

// Whi/Wlo: [3][128][256] ushort, row j = concat(Wl[j][:], Wr[j][:])
__global__ void wprep_kernel(const float* __restrict__ Wl, const float* __restrict__ Wr,
                             unsigned short* __restrict__ Whi, unsigned short* __restrict__ Wlo) {
    int t = blockIdx.x * 256 + threadIdx.x;
    if (t >= 3 * 128 * 256) return;
    const int L = t >> 15;
    const int r = t & 32767;
    const int j = r >> 8;
    const int k = r & 255;
    const float x = (k < 128) ? Wl[((size_t)L * 128 + j) * 128 + k]
                              : Wr[((size_t)L * 128 + j) * 128 + (k - 128)];
    const unsigned int p = packbf(x);
    Whi[t] = (unsigned short)(p >> 16);
    Wlo[t] = (unsigned short)(p & 0xFFFFu);
}

// layer-0 h (node_features fp32) -> packed h-part of A (k in [128,256))
__global__ void cvt0_kernel(const float* __restrict__ nf, unsigned int* __restrict__ Apk) {
    int t = blockIdx.x * 256 + threadIdx.x;   // one thread per 4 elems
    if (t >= N_NODES * 32) return;
    const int n  = t >> 5;
    const int k4 = (t & 31) * 4;
    const float4 v = *reinterpret_cast<const float4*>(nf + (size_t)n * D + k4);
    u32x4 o;
    o.x = packbf(v.x); o.y = packbf(v.y); o.z = packbf(v.z); o.w = packbf(v.w);
    *reinterpret_cast<u32x4*>(Apk + (size_t)n * 256 + 128 + k4) = o;
}

// ---------------- aggregation: mean part of A (k in [0,128)) ----------------
// Wave-per-node; gathers packed h rows (512B/row, uint2 per lane), scalar
// edge indices, 8-edge clamped+weighted chunks; writes packed mean.

__global__ __launch_bounds__(256, 8)
void agg_kernel(unsigned int* __restrict__ Apk,
                const int* __restrict__ row_start, const int* __restrict__ ssrc) {
    const int lane = threadIdx.x & 63;
    const int wave = threadIdx.x >> 6;
    const int n = blockIdx.x * 4 + wave;
    if (n >= N_NODES) return;
    const int e0 = __builtin_amdgcn_readfirstlane(row_start[n]);
    const int e1 = __builtin_amdgcn_readfirstlane(row_start[n + 1]);
    const int off = lane * 2;
    const unsigned int* __restrict__ H = Apk + 128 + off;   // h-part, row stride 256

    float a0 = 0.f, a1 = 0.f;
    #pragma unroll 1
    for (int e = e0; e < e1; e += 8) {
        const int el = e1 - 1;
        const int s0 = ssrc[min(e + 0, el)];
        const int s1 = ssrc[min(e + 1, el)];
        const int s2 = ssrc[min(e + 2, el)];
        const int s3 = ssrc[min(e + 3, el)];
        const int s4 = ssrc[min(e + 4, el)];
        const int s5 = ssrc[min(e + 5, el)];
        const int s6 = ssrc[min(e + 6, el)];
        const int s7 = ssrc[min(e + 7, el)];
        const uint2 v0 = *reinterpret_cast<const uint2*>(H + (size_t)s0 * 256);
        const uint2 v1 = *reinterpret_cast<const uint2*>(H + (size_t)s1 * 256);
        const uint2 v2 = *reinterpret_cast<const uint2*>(H + (size_t)s2 * 256);
        const uint2 v3 = *reinterpret_cast<const uint2*>(H + (size_t)s3 * 256);
        const uint2 v4 = *reinterpret_cast<const uint2*>(H + (size_t)s4 * 256);
        const uint2 v5 = *reinterpret_cast<const uint2*>(H + (size_t)s5 * 256);
        const uint2 v6 = *reinterpret_cast<const uint2*>(H + (size_t)s6 * 256);
        const uint2 v7 = *reinterpret_cast<const uint2*>(H + (size_t)s7 * 256);
        const float w1 = (e + 1 < e1) ? 1.f : 0.f;
        const float w2 = (e + 2 < e1) ? 1.f : 0.f;
        const float w3 = (e + 3 < e1) ? 1.f : 0.f;
        const float w4 = (e + 4 < e1) ? 1.f : 0.f;
        const float w5 = (e + 5 < e1) ? 1.f : 0.f;
        const float w6 = (e + 6 < e1) ? 1.f : 0.f;
        const float w7 = (e + 7 < e1) ? 1.f : 0.f;
        a0 += unpackbf(v0.x);                    a1 += unpackbf(v0.y);
        a0 = fmaf(unpackbf(v1.x), w1, a0);       a1 = fmaf(unpackbf(v1.y), w1, a1);
        a0 = fmaf(unpackbf(v2.x), w2, a0);       a1 = fmaf(unpackbf(v2.y), w2, a1);
        a0 = fmaf(unpackbf(v3.x), w3, a0);       a1 = fmaf(unpackbf(v3.y), w3, a1);
        a0 = fmaf(unpackbf(v4.x), w4, a0);       a1 = fmaf(unpackbf(v4.y), w4, a1);
        a0 = fmaf(unpackbf(v5.x), w5, a0);       a1 = fmaf(unpackbf(v5.y), w5, a1);
        a0 = fmaf(unpackbf(v6.x), w6, a0);       a1 = fmaf(unpackbf(v6.y), w6, a1);
        a0 = fmaf(unpackbf(v7.x), w7, a0);       a1 = fmaf(unpackbf(v7.y), w7, a1);
    }
    const float inv = 1.f / (float)max(e1 - e0, 1);
    uint2 w;
    w.x = packbf(a0 * inv);
    w.y = packbf(a1 * inv);
    *reinterpret_cast<uint2*>(Apk + (size_t)n * 256 + off) = w;
}

// ---------------- MFMA GEMM + LN + ReLU + residual ----------------
// Block: 4 waves x 16-node m-tiles = 64 nodes. K=256 (mean|h), N=128.
// Weights LDS-staged per K-half (Bhi/Blo [128][128] ushort = 64 KB, XOR
// granule swizzle -> conflict-free ds_write_b128 / ds_read_b128).
// A fragments loaded once, asm-pinned against rematerialization.
// bf16x3 product: AH*BH + AL*BH + AH*BL. MODE 0: packed h-out into Apk
// h-part (same element as residual read -> no hazard). MODE 1: fp32 out.

template<int MODE>
__global__ __launch_bounds__(256, 2)
void gemm_kernel(unsigned int* __restrict__ Apk,
                 float* __restrict__ outF,
                 const unsigned short* __restrict__ Whi,
                 const unsigned short* __restrict__ Wlo,
                 const float* __restrict__ bl,
                 const float* __restrict__ gamma,
                 const float* __restrict__ beta) {
    __shared__ unsigned short Bs[2][128][128];   // 64 KB, granule-swizzled

    const int tid  = threadIdx.x;
    const int lane = tid & 63;
    const int wave = tid >> 6;
    const int mt0  = blockIdx.x * 4 + wave;
    const int mt   = min(mt0, MTILES - 1);       // clamp; stores masked below
    const int rl   = lane & 15;
    const int kg   = lane >> 4;
    const int n    = mt * 16 + rl;
    const int swz  = rl & 7;

    // ---- A fragments: 8 K-tiles (full K=256), hi & lo, pinned ----
    bf16x8 AH[8], AL[8];
    {
        const unsigned int* __restrict__ ar = Apk + (size_t)n * 256 + kg * 8;
        #pragma unroll
        for (int kt = 0; kt < 8; ++kt) {
            const u32x4 p = *reinterpret_cast<const u32x4*>(ar + kt * 32);
            const u32x4 q = *reinterpret_cast<const u32x4*>(ar + kt * 32 + 4);
            u32x4 hw, lw;
            hw.x = (p.y & 0xFFFF0000u) | (p.x >> 16);
            hw.y = (p.w & 0xFFFF0000u) | (p.z >> 16);
            hw.z = (q.y & 0xFFFF0000u) | (q.x >> 16);
            hw.w = (q.w & 0xFFFF0000u) | (q.z >> 16);
            lw.x = (p.x & 0xFFFFu) | (p.y << 16);
            lw.y = (p.z & 0xFFFFu) | (p.w << 16);
            lw.z = (q.x & 0xFFFFu) | (q.y << 16);
            lw.w = (q.z & 0xFFFFu) | (q.w << 16);
            asm volatile("" : "+v"(hw), "+v"(lw));   // forbid remat; keep resident
            AH[kt] = __builtin_bit_cast(bf16x8, hw);
            AL[kt] = __builtin_bit_cast(bf16x8, lw);
        }
    }

    f32x4 AC[8];
    #pragma unroll
    for (int jt = 0; jt < 8; ++jt) { AC[jt].x = 0.f; AC[jt].y = 0.f; AC[jt].z = 0.f; AC[jt].w = 0.f; }

    #pragma unroll 1
    for (int kh = 0; kh < 2; ++kh) {
        if (kh) __syncthreads();                 // all waves done reading half 0

        // ---- stage K-half of Whi/Wlo into swizzled LDS ----
        #pragma unroll
        for (int q8 = 0; q8 < 8; ++q8) {
            const int c  = q8 * 256 + tid;       // chunk 0..2047
            const int j  = c >> 4;               // row 0..127
            const int k8 = c & 15;               // 16B granule within half
            const size_t gsrc = (size_t)j * 256 + kh * 128 + k8 * 8;
            const short8 vh = *reinterpret_cast<const short8*>(Whi + gsrc);
            const short8 vl = *reinterpret_cast<const short8*>(Wlo + gsrc);
            const int gd = ((k8 ^ (j & 7)) * 8);
            *reinterpret_cast<short8*>(&Bs[0][j][gd]) = vh;
            *reinterpret_cast<short8*>(&Bs[1][j][gd]) = vl;
        }
        __syncthreads();

        // ---- MFMA over this K-half ----
        #pragma unroll
        for (int jt = 0; jt < 8; ++jt) {
            const int j = jt * 16 + rl;
            #pragma unroll
            for (int kt = 0; kt < 4; ++kt) {
                const int gd = (((kt * 4 + kg) ^ swz) * 8);
                const bf16x8 BH = __builtin_bit_cast(bf16x8,
                    *reinterpret_cast<const short8*>(&Bs[0][j][gd]));
                const bf16x8 BL = __builtin_bit_cast(bf16x8,
                    *reinterpret_cast<const short8*>(&Bs[1][j][gd]));
                const int ka = kh * 4 + kt;
                AC[jt] = __builtin_amdgcn_mfma_f32_16x16x32_bf16(AH[ka], BH, AC[jt], 0, 0, 0);
                AC[jt] = __builtin_amdgcn_mfma_f32_16x16x32_bf16(AL[ka], BH, AC[jt], 0, 0, 0);
                AC[jt] = __builtin_amdgcn_mfma_f32_16x16x32_bf16(AH[ka], BL, AC[jt], 0, 0, 0);
            }
        }
    }

    // ---- bias ----
    #pragma unroll
    for (int jt = 0; jt < 8; ++jt) {
        const float bb = bl[jt * 16 + rl];
        AC[jt].x += bb; AC[jt].y += bb; AC[jt].z += bb; AC[jt].w += bb;
    }

    // ---- LayerNorm stats: row = mt*16 + kg*4 + r, spread over 16 lanes x 8 jt
    float mu[4], rs[4];
    #pragma unroll
    for (int r = 0; r < 4; ++r) {
        float s1 = 0.f, s2 = 0.f;
        #pragma unroll
        for (int jt = 0; jt < 8; ++jt) {
            const float v = AC[jt][r];
            s1 += v;
            s2 = fmaf(v, v, s2);
        }
        #pragma unroll
        for (int m = 1; m < 16; m <<= 1) {
            s1 += __shfl_xor(s1, m);
            s2 += __shfl_xor(s2, m);
        }
        mu[r] = s1 * (1.f / 128.f);
        const float var = fmaf(s2, 1.f / 128.f, -mu[r] * mu[r]);
        rs[r] = 1.f / sqrtf(var + EPS);
    }

    // ---- LN + ReLU + residual + store (masked for clamped tail waves) ----
    if (mt0 < MTILES) {
        #pragma unroll
        for (int jt = 0; jt < 8; ++jt) {
            const int j = jt * 16 + rl;
            const float g  = gamma[j];
            const float be = beta[j];
            #pragma unroll
            for (int r = 0; r < 4; ++r) {
                const int row = mt * 16 + kg * 4 + r;
                unsigned int* hp = Apk + (size_t)row * 256 + 128 + j;
                const float res = unpackbf(*hp);
                const float v = fmaxf(fmaf((AC[jt][r] - mu[r]) * rs[r], g, be), 0.f);
                const float o = res + v;
                if (MODE == 0) *hp = packbf(o);
                else           outF[(size_t)row * D + j] = o;
            }
        }
    }
}

// ---------------- launch ----------------

extern "C" void kernel_launch(void* const* d_in, const int* in_sizes, int n_in,
                              void* d_out, int out_size, void* d_ws, size_t ws_size,
                              hipStream_t stream) {
    const float* nf = (const float*)d_in[0];
    const int*   ei = (const int*)d_in[1];        // [2][E]: src row, dst row
    const float* Wl = (const float*)d_in[2];      // [3][128][128]
    const float* bl = (const float*)d_in[3];      // [3][128]
    const float* Wr = (const float*)d_in[4];
    const float* gm = (const float*)d_in[5];
    const float* bt = (const float*)d_in[6];
    float* out = (float*)d_out;

    char* w = (char*)d_ws;
    size_t off = 0;
    auto carve = [&](size_t bytes) -> char* {
        char* p = w + off;
        off = (off + bytes + 511) & ~(size_t)511;
        return p;
    };
    int*   deg       = (int*)carve((size_t)N_NODES * 4);
    int*   row_start = (int*)carve((size_t)(N_NODES + 1) * 4);
    int*   cursor    = (int*)carve((size_t)N_NODES * 4);
    int*   bsum      = (int*)carve((size_t)SCAN_B * 4);
    int*   bbase     = (int*)carve((size_t)SCAN_B * 4);
    int*   ssrc      = (int*)carve((size_t)N_EDGES * 4);
    unsigned int*   Apk = (unsigned int*)carve((size_t)N_NODES * 256 * 4);   // 51.2 MB
    unsigned short* Whi = (unsigned short*)carve((size_t)3 * 128 * 256 * 2);
    unsigned short* Wlo = (unsigned short*)carve((size_t)3 * 128 * 256 * 2);

    const int* src = ei;
    const int* dst = ei + N_EDGES;

    hipMemsetAsync(deg, 0, (size_t)N_NODES * 4, stream);
    count_kernel<<<(N_EDGES + 255) / 256, 256, 0, stream>>>(dst, deg);
    block_reduce_kernel<<<SCAN_B, 256, 0, stream>>>(deg, bsum);
    block_scan_kernel<<<1, 256, 0, stream>>>(bsum, bbase);
    expand_kernel<<<SCAN_B, 256, 0, stream>>>(deg, bbase, row_start, cursor);
    fill_kernel<<<(N_EDGES + 255) / 256, 256, 0, stream>>>(src, dst, cursor, ssrc);

    wprep_kernel<<<(3 * 128 * 256 + 255) / 256, 256, 0, stream>>>(Wl, Wr, Whi, Wlo);
    cvt0_kernel<<<(N_NODES * 32 + 255) / 256, 256, 0, stream>>>(nf, Apk);

    const int GA = (N_NODES + 3) / 4;        // 12500
    const int GG = (MTILES + 3) / 4;         // 782

    // layer 0
    agg_kernel<<<GA, THREADS, 0, stream>>>(Apk, row_start, ssrc);
    gemm_kernel<0><<<GG, THREADS, 0, stream>>>(Apk, nullptr, Whi, Wlo, bl, gm, bt);
    // layer 1
    agg_kernel<<<GA, THREADS, 0, stream>>>(Apk, row_start, ssrc);
    gemm_kernel<0><<<GG, THREADS, 0, stream>>>(Apk, nullptr,
                                               Whi + 32768, Wlo + 32768,
                                               bl + D, gm + D, bt + D);
    // layer 2
    agg_kernel<<<GA, THREADS, 0, stream>>>(Apk, row_start, ssrc);
    gemm_kernel<1><<<GG, THREADS, 0, stream>>>(Apk, out,
                                               Whi + 65536, Wlo + 65536,
                                               bl + 2 * D, gm + 2 * D, bt + 2 * D);
}

// Round 7
// 432.817 us; speedup vs baseline: 3.6841x; 3.6841x over previous
//
#include <hip/hip_runtime.h>

#define N_NODES 50000
#define N_EDGES 800000
#define D       128
#define THREADS 256
#define EPS     1e-5f
#define SCAN_B  196     // ceil(N_NODES/256)
#define MTILES  3125    // N_NODES / 16

typedef __attribute__((ext_vector_type(8))) __bf16  bf16x8;
typedef __attribute__((ext_vector_type(8))) short   short8;
typedef __attribute__((ext_vector_type(4))) float   f32x4;
typedef __attribute__((ext_vector_type(4))) unsigned int u32x4;

// pack fp32 -> (bf16_hi << 16) | bf16_lo  (bf16x2 split: hi+lo ~= x to ~2^-17 rel)
__device__ inline unsigned int packbf(float x) {
    unsigned int u  = __float_as_uint(x);
    unsigned int hi = (u + 0x7FFFu + ((u >> 16) & 1u)) >> 16;
    float hf = __uint_as_float(hi << 16);
    float lo = x - hf;
    unsigned int ul  = __float_as_uint(lo);
    unsigned int l16 = (ul + 0x7FFFu + ((ul >> 16) & 1u)) >> 16;
    return (hi << 16) | (l16 & 0xFFFFu);
}
__device__ inline float unpackbf(unsigned int u) {
    return __uint_as_float(u & 0xFFFF0000u) + __uint_as_float(u << 16);
}

// ---------------- CSR build ----------------

__global__ void count_kernel(const int* __restrict__ dst, int* __restrict__ deg) {
    int e = blockIdx.x * 256 + threadIdx.x;
    if (e < N_EDGES) atomicAdd(&deg[dst[e]], 1);
}

__global__ void block_reduce_kernel(const int* __restrict__ deg, int* __restrict__ bsum) {
    __shared__ int red[256];
    int i = blockIdx.x * 256 + threadIdx.x;
    red[threadIdx.x] = (i < N_NODES) ? deg[i] : 0;
    __syncthreads();
    for (int off = 128; off > 0; off >>= 1) {
        if (threadIdx.x < off) red[threadIdx.x] += red[threadIdx.x + off];
        __syncthreads();
    }
    if (threadIdx.x == 0) bsum[blockIdx.x] = red[0];
}

__global__ void block_scan_kernel(const int* __restrict__ bsum, int* __restrict__ bbase) {
    __shared__ int s[256];
    const int t = threadIdx.x;
    const int v = (t < SCAN_B) ? bsum[t] : 0;
    s[t] = v;
    __syncthreads();
    for (int off = 1; off < 256; off <<= 1) {
        int add = (t >= off) ? s[t - off] : 0;
        __syncthreads();
        s[t] += add;
        __syncthreads();
    }
    if (t < SCAN_B) bbase[t] = s[t] - v;   // exclusive
}

__global__ void expand_kernel(const int* __restrict__ deg, const int* __restrict__ bbase,
                              int* __restrict__ row_start, int* __restrict__ cursor) {
    __shared__ int s[256];
    const int t = threadIdx.x;
    const int i = blockIdx.x * 256 + t;
    const int v = (i < N_NODES) ? deg[i] : 0;
    s[t] = v;
    __syncthreads();
    for (int off = 1; off < 256; off <<= 1) {
        int add = (t >= off) ? s[t - off] : 0;
        __syncthreads();
        s[t] += add;
        __syncthreads();
    }
    const int excl = bbase[blockIdx.x] + s[t] - v;
    if (i < N_NODES) { row_start[i] = excl; cursor[i] = excl; }
    if (i == N_NODES - 1) row_start[N_NODES] = excl + v;
}

__global__ void fill_kernel(const int* __restrict__ src, const int* __restrict__ dst,
                            int* __restrict__ cursor, int* __restrict__ ssrc) {
    int e = blockIdx.x * 256 + threadIdx.x;
    if (e < N_EDGES) {
        int d = dst[e];
        int p = atomicAdd(&cursor[d], 1);
        ssrc[p] = src[e];
    }
}

// ---------------- prep: weights + layer-0 h into packed/bf16 form ----------

// Whi/Wlo: [3][128][256] ushort, row j = concat(Wl[j][:], Wr[j][:])
__global__ void wprep_kernel(const float* __restrict__ Wl, const float* __restrict__ Wr,
                             unsigned short* __restrict__ Whi, unsigned short* __restrict__ Wlo) {
    int t = blockIdx.x * 256 + threadIdx.x;
    if (t >= 3 * 128 * 256) return;
    const int L = t >> 15;
    const int r = t & 32767;
    const int j = r >> 8;
    const int k = r & 255;
    const float x = (k < 128) ? Wl[((size_t)L * 128 + j) * 128 + k]
                              : Wr[((size_t)L * 128 + j) * 128 + (k - 128)];
    const unsigned int p = packbf(x);
    Whi[t] = (unsigned short)(p >> 16);
    Wlo[t] = (unsigned short)(p & 0xFFFFu);
}

// layer-0 h (node_features fp32) -> packed h-part of A (k in [128,256))
__global__ void cvt0_kernel(const float* __restrict__ nf, unsigned int* __restrict__ Apk) {
    int t = blockIdx.x * 256 + threadIdx.x;   // one thread per 4 elems
    if (t >= N_NODES * 32) return;
    const int n  = t >> 5;
    const int k4 = (t & 31) * 4;
    const float4 v = *reinterpret_cast<const float4*>(nf + (size_t)n * D + k4);
    u32x4 o;
    o.x = packbf(v.x); o.y = packbf(v.y); o.z = packbf(v.z); o.w = packbf(v.w);
    *reinterpret_cast<u32x4*>(Apk + (size_t)n * 256 + 128 + k4) = o;
}

// ---------------- aggregation: mean part of A (k in [0,128)) ----------------

__global__ __launch_bounds__(256, 8)
void agg_kernel(unsigned int* __restrict__ Apk,
                const int* __restrict__ row_start, const int* __restrict__ ssrc) {
    const int lane = threadIdx.x & 63;
    const int wave = threadIdx.x >> 6;
    const int n = blockIdx.x * 4 + wave;
    if (n >= N_NODES) return;
    const int e0 = __builtin_amdgcn_readfirstlane(row_start[n]);
    const int e1 = __builtin_amdgcn_readfirstlane(row_start[n + 1]);
    const int off = lane * 2;
    const unsigned int* __restrict__ H = Apk + 128 + off;   // h-part, row stride 256

    float a0 = 0.f, a1 = 0.f;
    #pragma unroll 1
    for (int e = e0; e < e1; e += 8) {
        const int el = e1 - 1;
        const int s0 = ssrc[min(e + 0, el)];
        const int s1 = ssrc[min(e + 1, el)];
        const int s2 = ssrc[min(e + 2, el)];
        const int s3 = ssrc[min(e + 3, el)];
        const int s4 = ssrc[min(e + 4, el)];
        const int s5 = ssrc[min(e + 5, el)];
        const int s6 = ssrc[min(e + 6, el)];
        const int s7 = ssrc[min(e + 7, el)];
        const uint2 v0 = *reinterpret_cast<const uint2*>(H + (size_t)s0 * 256);
        const uint2 v1 = *reinterpret_cast<const uint2*>(H + (size_t)s1 * 256);
        const uint2 v2 = *reinterpret_cast<const uint2*>(H + (size_t)s2 * 256);
        const uint2 v3 = *reinterpret_cast<const uint2*>(H + (size_t)s3 * 256);
        const uint2 v4 = *reinterpret_cast<const uint2*>(H + (size_t)s4 * 256);
        const uint2 v5 = *reinterpret_cast<const uint2*>(H + (size_t)s5 * 256);
        const uint2 v6 = *reinterpret_cast<const uint2*>(H + (size_t)s6 * 256);
        const uint2 v7 = *reinterpret_cast<const uint2*>(H + (size_t)s7 * 256);
        const float w1 = (e + 1 < e1) ? 1.f : 0.f;
        const float w2 = (e + 2 < e1) ? 1.f : 0.f;
        const float w3 = (e + 3 < e1) ? 1.f : 0.f;
        const float w4 = (e + 4 < e1) ? 1.f : 0.f;
        const float w5 = (e + 5 < e1) ? 1.f : 0.f;
        const float w6 = (e + 6 < e1) ? 1.f : 0.f;
        const float w7 = (e + 7 < e1) ? 1.f : 0.f;
        a0 += unpackbf(v0.x);                    a1 += unpackbf(v0.y);
        a0 = fmaf(unpackbf(v1.x), w1, a0);       a1 = fmaf(unpackbf(v1.y), w1, a1);
        a0 = fmaf(unpackbf(v2.x), w2, a0);       a1 = fmaf(unpackbf(v2.y), w2, a1);
        a0 = fmaf(unpackbf(v3.x), w3, a0);       a1 = fmaf(unpackbf(v3.y), w3, a1);
        a0 = fmaf(unpackbf(v4.x), w4, a0);       a1 = fmaf(unpackbf(v4.y), w4, a1);
        a0 = fmaf(unpackbf(v5.x), w5, a0);       a1 = fmaf(unpackbf(v5.y), w5, a1);
        a0 = fmaf(unpackbf(v6.x), w6, a0);       a1 = fmaf(unpackbf(v6.y), w6, a1);
        a0 = fmaf(unpackbf(v7.x), w7, a0);       a1 = fmaf(unpackbf(v7.y), w7, a1);
    }
    const float inv = 1.f / (float)max(e1 - e0, 1);
    uint2 w;
    w.x = packbf(a0 * inv);
    w.y = packbf(a1 * inv);
    *reinterpret_cast<uint2*>(Apk + (size_t)n * 256 + off) = w;
}

// ---------------- MFMA GEMM + LN + ReLU + residual ----------------
// Block: 4 waves x 16-node m-tiles. K=256 staged in 4 quarters (FULLY
// UNROLLED -> all AH/AL indices compile-time -> registers, no scratch).
// LDS: linear fragment-order layout Bs[hl][tile][slot][8], slot=rl*4+kg:
// each wave's ds_read_b128 covers a contiguous 1024B block (conflict-free),
// with compile-time tile offsets. 32KB -> 3 blocks/CU at VGPR<=168.

template<int MODE>
__global__ __launch_bounds__(256, 3)
void gemm_kernel(unsigned int* __restrict__ Apk,
                 float* __restrict__ outF,
                 const unsigned short* __restrict__ Whi,
                 const unsigned short* __restrict__ Wlo,
                 const float* __restrict__ bl,
                 const float* __restrict__ gamma,
                 const float* __restrict__ beta) {
    // [hi/lo][tile = jt*2+ktl][slot = rl*4+kg][8 ushort] : 32 KB
    __shared__ unsigned short Bs[2][16][64][8];

    const int tid  = threadIdx.x;
    const int lane = tid & 63;
    const int wave = tid >> 6;
    const int mt0  = blockIdx.x * 4 + wave;
    const int mt   = min(mt0, MTILES - 1);       // clamp; stores masked below
    const int rl   = lane & 15;
    const int kg   = lane >> 4;
    const int n    = mt * 16 + rl;
    const int slot = rl * 4 + kg;                // read slot (lane permutation)

    // ---- A fragments: 8 K-tiles (full K=256), hi & lo, pinned in regs ----
    bf16x8 AH[8], AL[8];
    {
        const unsigned int* __restrict__ ar = Apk + (size_t)n * 256 + kg * 8;
        #pragma unroll
        for (int kt = 0; kt < 8; ++kt) {
            const u32x4 p = *reinterpret_cast<const u32x4*>(ar + kt * 32);
            const u32x4 q = *reinterpret_cast<const u32x4*>(ar + kt * 32 + 4);
            u32x4 hw, lw;
            hw.x = (p.y & 0xFFFF0000u) | (p.x >> 16);
            hw.y = (p.w & 0xFFFF0000u) | (p.z >> 16);
            hw.z = (q.y & 0xFFFF0000u) | (q.x >> 16);
            hw.w = (q.w & 0xFFFF0000u) | (q.z >> 16);
            lw.x = (p.x & 0xFFFFu) | (p.y << 16);
            lw.y = (p.z & 0xFFFFu) | (p.w << 16);
            lw.z = (q.x & 0xFFFFu) | (q.y << 16);
            lw.w = (q.z & 0xFFFFu) | (q.w << 16);
            asm volatile("" : "+v"(hw), "+v"(lw));   // forbid remat
            AH[kt] = __builtin_bit_cast(bf16x8, hw);
            AL[kt] = __builtin_bit_cast(bf16x8, lw);
        }
    }

    f32x4 AC[8];
    #pragma unroll
    for (int jt = 0; jt < 8; ++jt) { AC[jt].x = 0.f; AC[jt].y = 0.f; AC[jt].z = 0.f; AC[jt].w = 0.f; }

    // ---- K in 4 quarters of 64; FULL unroll keeps AH/AL indices static ----
    #pragma unroll
    for (int qu = 0; qu < 4; ++qu) {
        if (qu) __syncthreads();                 // prev quarter fully consumed

        // stage quarter: 1024 granules x (hi,lo); coalesced 16B global loads
        #pragma unroll
        for (int q = 0; q < 4; ++q) {
            const int c  = q * 256 + tid;        // 0..1023
            const int j  = c >> 3;               // row 0..127
            const int G  = c & 7;                // 16B granule within quarter
            const size_t gsrc = (size_t)j * 256 + qu * 64 + G * 8;
            const short8 vh = *reinterpret_cast<const short8*>(Whi + gsrc);
            const short8 vl = *reinterpret_cast<const short8*>(Wlo + gsrc);
            const int tile = (j >> 4) * 2 + (G >> 2);
            const int slw  = (j & 15) * 4 + (G & 3);
            *reinterpret_cast<short8*>(&Bs[0][tile][slw][0]) = vh;
            *reinterpret_cast<short8*>(&Bs[1][tile][slw][0]) = vl;
        }
        __syncthreads();

        #pragma unroll
        for (int jt = 0; jt < 8; ++jt) {
            #pragma unroll
            for (int ktl = 0; ktl < 2; ++ktl) {
                const bf16x8 BH = __builtin_bit_cast(bf16x8,
                    *reinterpret_cast<const short8*>(&Bs[0][jt * 2 + ktl][slot][0]));
                const bf16x8 BL = __builtin_bit_cast(bf16x8,
                    *reinterpret_cast<const short8*>(&Bs[1][jt * 2 + ktl][slot][0]));
                const int ka = qu * 2 + ktl;     // compile-time after unroll
                AC[jt] = __builtin_amdgcn_mfma_f32_16x16x32_bf16(AH[ka], BH, AC[jt], 0, 0, 0);
                AC[jt] = __builtin_amdgcn_mfma_f32_16x16x32_bf16(AL[ka], BH, AC[jt], 0, 0, 0);
                AC[jt] = __builtin_amdgcn_mfma_f32_16x16x32_bf16(AH[ka], BL, AC[jt], 0, 0, 0);
            }
        }
    }

    // ---- bias ----
    #pragma unroll
    for (int jt = 0; jt < 8; ++jt) {
        const float bb = bl[jt * 16 + rl];
        AC[jt].x += bb; AC[jt].y += bb; AC[jt].z += bb; AC[jt].w += bb;
    }

    // ---- LayerNorm stats: row = mt*16 + kg*4 + r, spread over 16 lanes x 8 jt
    float mu[4], rs[4];
    #pragma unroll
    for (int r = 0; r < 4; ++r) {
        float s1 = 0.f, s2 = 0.f;
        #pragma unroll
        for (int jt = 0; jt < 8; ++jt) {
            const float v = AC[jt][r];
            s1 += v;
            s2 = fmaf(v, v, s2);
        }
        #pragma unroll
        for (int m = 1; m < 16; m <<= 1) {
            s1 += __shfl_xor(s1, m);
            s2 += __shfl_xor(s2, m);
        }
        mu[r] = s1 * (1.f / 128.f);
        const float var = fmaf(s2, 1.f / 128.f, -mu[r] * mu[r]);
        rs[r] = 1.f / sqrtf(var + EPS);
    }

    // ---- LN + ReLU + residual + store (masked for clamped tail waves) ----
    if (mt0 < MTILES) {
        #pragma unroll
        for (int jt = 0; jt < 8; ++jt) {
            const int j = jt * 16 + rl;
            const float g  = gamma[j];
            const float be = beta[j];
            #pragma unroll
            for (int r = 0; r < 4; ++r) {
                const int row = mt * 16 + kg * 4 + r;
                unsigned int* hp = Apk + (size_t)row * 256 + 128 + j;
                const float res = unpackbf(*hp);
                const float v = fmaxf(fmaf((AC[jt][r] - mu[r]) * rs[r], g, be), 0.f);
                const float o = res + v;
                if (MODE == 0) *hp = packbf(o);
                else           outF[(size_t)row * D + j] = o;
            }
        }
    }
}

// ---------------- launch ----------------

extern "C" void kernel_launch(void* const* d_in, const int* in_sizes, int n_in,
                              void* d_out, int out_size, void* d_ws, size_t ws_size,
                              hipStream_t stream) {
    const float* nf = (const float*)d_in[0];
    const int*   ei = (const int*)d_in[1];        // [2][E]: src row, dst row
    const float* Wl = (const float*)d_in[2];      // [3][128][128]
    const float* bl = (const float*)d_in[3];      // [3][128]
    const float* Wr = (const float*)d_in[4];
    const float* gm = (const float*)d_in[5];
    const float* bt = (const float*)d_in[6];
    float* out = (float*)d_out;

    char* w = (char*)d_ws;
    size_t off = 0;
    auto carve = [&](size_t bytes) -> char* {
        char* p = w + off;
        off = (off + bytes + 511) & ~(size_t)511;
        return p;
    };
    int*   deg       = (int*)carve((size_t)N_NODES * 4);
    int*   row_start = (int*)carve((size_t)(N_NODES + 1) * 4);
    int*   cursor    = (int*)carve((size_t)N_NODES * 4);
    int*   bsum      = (int*)carve((size_t)SCAN_B * 4);
    int*   bbase     = (int*)carve((size_t)SCAN_B * 4);
    int*   ssrc      = (int*)carve((size_t)N_EDGES * 4);
    unsigned int*   Apk = (unsigned int*)carve((size_t)N_NODES * 256 * 4);   // 51.2 MB
    unsigned short* Whi = (unsigned short*)carve((size_t)3 * 128 * 256 * 2);
    unsigned short* Wlo = (unsigned short*)carve((size_t)3 * 128 * 256 * 2);

    const int* src = ei;
    const int* dst = ei + N_EDGES;

    hipMemsetAsync(deg, 0, (size_t)N_NODES * 4, stream);
    count_kernel<<<(N_EDGES + 255) / 256, 256, 0, stream>>>(dst, deg);
    block_reduce_kernel<<<SCAN_B, 256, 0, stream>>>(deg, bsum);
    block_scan_kernel<<<1, 256, 0, stream>>>(bsum, bbase);
    expand_kernel<<<SCAN_B, 256, 0, stream>>>(deg, bbase, row_start, cursor);
    fill_kernel<<<(N_EDGES + 255) / 256, 256, 0, stream>>>(src, dst, cursor, ssrc);

    wprep_kernel<<<(3 * 128 * 256 + 255) / 256, 256, 0, stream>>>(Wl, Wr, Whi, Wlo);
    cvt0_kernel<<<(N_NODES * 32 + 255) / 256, 256, 0, stream>>>(nf, Apk);

    const int GA = (N_NODES + 3) / 4;        // 12500
    const int GG = (MTILES + 3) / 4;         // 782

    // layer 0
    agg_kernel<<<GA, THREADS, 0, stream>>>(Apk, row_start, ssrc);
    gemm_kernel<0><<<GG, THREADS, 0, stream>>>(Apk, nullptr, Whi, Wlo, bl, gm, bt);
    // layer 1
    agg_kernel<<<GA, THREADS, 0, stream>>>(Apk, row_start, ssrc);
    gemm_kernel<0><<<GG, THREADS, 0, stream>>>(Apk, nullptr,
                                               Whi + 32768, Wlo + 32768,
                                               bl + D, gm + D, bt + D);
    // layer 2
    agg_kernel<<<GA, THREADS, 0, stream>>>(Apk, row_start, ssrc);
    gemm_kernel<1><<<GG, THREADS, 0, stream>>>(Apk, out,
                                               Whi + 65536, Wlo + 65536,
                                               bl + 2 * D, gm + 2 * D, bt + 2 * D);
}

// Round 8
// 365.899 us; speedup vs baseline: 4.3578x; 1.1829x over previous
//
#include <hip/hip_runtime.h>

#define N_NODES 50000
#define N_EDGES 800000
#define D       128
#define THREADS 256
#define EPS     1e-5f
#define SCAN_B  196     // ceil(N_NODES/256)
#define MTILES  3125    // N_NODES / 16

typedef __attribute__((ext_vector_type(8))) __bf16  bf16x8;
typedef __attribute__((ext_vector_type(8))) short   short8;
typedef __attribute__((ext_vector_type(4))) float   f32x4;
typedef __attribute__((ext_vector_type(4))) unsigned int u32x4;

// fp32 -> bf16 (rne), as low 16 bits
__device__ inline unsigned int bfround(float x) {
    unsigned int u = __float_as_uint(x);
    return (u + 0x7FFFu + ((u >> 16) & 1u)) >> 16;
}
// pack fp32 -> (bf16_hi << 16) | bf16_lo   (hi+lo ~= x to ~2^-17 rel)
__device__ inline unsigned int packbf(float x) {
    unsigned int hi = bfround(x);
    float lo = x - __uint_as_float(hi << 16);
    return (hi << 16) | (bfround(lo) & 0xFFFFu);
}
__device__ inline float unpackbf(unsigned int u) {
    return __uint_as_float(u & 0xFFFF0000u) + __uint_as_float(u << 16);
}

// ---------------- CSR build ----------------

__global__ void count_kernel(const int* __restrict__ dst, int* __restrict__ deg) {
    int e = blockIdx.x * 256 + threadIdx.x;
    if (e < N_EDGES) atomicAdd(&deg[dst[e]], 1);
}

__global__ void block_reduce_kernel(const int* __restrict__ deg, int* __restrict__ bsum) {
    __shared__ int red[256];
    int i = blockIdx.x * 256 + threadIdx.x;
    red[threadIdx.x] = (i < N_NODES) ? deg[i] : 0;
    __syncthreads();
    for (int off = 128; off > 0; off >>= 1) {
        if (threadIdx.x < off) red[threadIdx.x] += red[threadIdx.x + off];
        __syncthreads();
    }
    if (threadIdx.x == 0) bsum[blockIdx.x] = red[0];
}

__global__ void block_scan_kernel(const int* __restrict__ bsum, int* __restrict__ bbase) {
    __shared__ int s[256];
    const int t = threadIdx.x;
    const int v = (t < SCAN_B) ? bsum[t] : 0;
    s[t] = v;
    __syncthreads();
    for (int off = 1; off < 256; off <<= 1) {
        int add = (t >= off) ? s[t - off] : 0;
        __syncthreads();
        s[t] += add;
        __syncthreads();
    }
    if (t < SCAN_B) bbase[t] = s[t] - v;   // exclusive
}

__global__ void expand_kernel(const int* __restrict__ deg, const int* __restrict__ bbase,
                              int* __restrict__ row_start, int* __restrict__ cursor) {
    __shared__ int s[256];
    const int t = threadIdx.x;
    const int i = blockIdx.x * 256 + t;
    const int v = (i < N_NODES) ? deg[i] : 0;
    s[t] = v;
    __syncthreads();
    for (int off = 1; off < 256; off <<= 1) {
        int add = (t >= off) ? s[t - off] : 0;
        __syncthreads();
        s[t] += add;
        __syncthreads();
    }
    const int excl = bbase[blockIdx.x] + s[t] - v;
    if (i < N_NODES) { row_start[i] = excl; cursor[i] = excl; }
    if (i == N_NODES - 1) row_start[N_NODES] = excl + v;
}

__global__ void fill_kernel(const int* __restrict__ src, const int* __restrict__ dst,
                            int* __restrict__ cursor, int* __restrict__ ssrc) {
    int e = blockIdx.x * 256 + threadIdx.x;
    if (e < N_EDGES) {
        int d = dst[e];
        int p = atomicAdd(&cursor[d], 1);
        __builtin_nontemporal_store(src[e], &ssrc[p]);   // bypass bouncing L2 lines
    }
}

// ---------------- prep ----------------

// Whi/Wlo: [3][128][256] ushort, row j = concat(Wl[j][:], Wr[j][:])
__global__ void wprep_kernel(const float* __restrict__ Wl, const float* __restrict__ Wr,
                             unsigned short* __restrict__ Whi, unsigned short* __restrict__ Wlo) {
    int t = blockIdx.x * 256 + threadIdx.x;
    if (t >= 3 * 128 * 256) return;
    const int L = t >> 15;
    const int r = t & 32767;
    const int j = r >> 8;
    const int k = r & 255;
    const float x = (k < 128) ? Wl[((size_t)L * 128 + j) * 128 + k]
                              : Wr[((size_t)L * 128 + j) * 128 + (k - 128)];
    const unsigned int p = packbf(x);
    Whi[t] = (unsigned short)(p >> 16);
    Wlo[t] = (unsigned short)(p & 0xFFFFu);
}

// layer-0: fp32 node_features -> packed Apk [n][128] and bf16 Hh [n][128]
__global__ void cvt0_kernel(const float* __restrict__ nf,
                            unsigned int* __restrict__ Apk,
                            unsigned short* __restrict__ Hh) {
    int t = blockIdx.x * 256 + threadIdx.x;   // one thread per 4 elems
    if (t >= N_NODES * 32) return;
    const int n  = t >> 5;
    const int k4 = (t & 31) * 4;
    const float4 v = *reinterpret_cast<const float4*>(nf + (size_t)n * D + k4);
    u32x4 o;
    o.x = packbf(v.x); o.y = packbf(v.y); o.z = packbf(v.z); o.w = packbf(v.w);
    *reinterpret_cast<u32x4*>(Apk + (size_t)n * 128 + k4) = o;
    uint2 hh;
    hh.x = (o.x >> 16) | (o.y & 0xFFFF0000u);
    hh.y = (o.z >> 16) | (o.w & 0xFFFF0000u);
    *reinterpret_cast<uint2*>((unsigned int*)Hh + (size_t)n * 64 + (k4 >> 1)) = hh;
}

// ---------------- aggregation: Mb[n][128] bf16 = mean of Hh[src] ----------------
// Wave-per-node; 256B bf16 rows (1 dword/lane); 16-deep clamped+weighted
// load pipeline; scalar edge indices.

__global__ __launch_bounds__(256, 8)
void agg_kernel(const unsigned short* __restrict__ Hh,
                unsigned short* __restrict__ Mb,
                const int* __restrict__ row_start, const int* __restrict__ ssrc) {
    const int lane = threadIdx.x & 63;
    const int wave = threadIdx.x >> 6;
    const int n = blockIdx.x * 4 + wave;
    if (n >= N_NODES) return;
    const int e0 = __builtin_amdgcn_readfirstlane(row_start[n]);
    const int e1 = __builtin_amdgcn_readfirstlane(row_start[n + 1]);
    const unsigned int* __restrict__ H = (const unsigned int*)Hh + lane;  // +64/row

    float a0 = 0.f, a1 = 0.f;
    #pragma unroll 1
    for (int e = e0; e < e1; e += 16) {
        const int el = e1 - 1;
        const int s0  = ssrc[min(e + 0,  el)];
        const int s1  = ssrc[min(e + 1,  el)];
        const int s2  = ssrc[min(e + 2,  el)];
        const int s3  = ssrc[min(e + 3,  el)];
        const int s4  = ssrc[min(e + 4,  el)];
        const int s5  = ssrc[min(e + 5,  el)];
        const int s6  = ssrc[min(e + 6,  el)];
        const int s7  = ssrc[min(e + 7,  el)];
        const int s8  = ssrc[min(e + 8,  el)];
        const int s9  = ssrc[min(e + 9,  el)];
        const int s10 = ssrc[min(e + 10, el)];
        const int s11 = ssrc[min(e + 11, el)];
        const int s12 = ssrc[min(e + 12, el)];
        const int s13 = ssrc[min(e + 13, el)];
        const int s14 = ssrc[min(e + 14, el)];
        const int s15 = ssrc[min(e + 15, el)];
        const unsigned int v0  = H[(size_t)s0  * 64];
        const unsigned int v1  = H[(size_t)s1  * 64];
        const unsigned int v2  = H[(size_t)s2  * 64];
        const unsigned int v3  = H[(size_t)s3  * 64];
        const unsigned int v4  = H[(size_t)s4  * 64];
        const unsigned int v5  = H[(size_t)s5  * 64];
        const unsigned int v6  = H[(size_t)s6  * 64];
        const unsigned int v7  = H[(size_t)s7  * 64];
        const unsigned int v8  = H[(size_t)s8  * 64];
        const unsigned int v9  = H[(size_t)s9  * 64];
        const unsigned int v10 = H[(size_t)s10 * 64];
        const unsigned int v11 = H[(size_t)s11 * 64];
        const unsigned int v12 = H[(size_t)s12 * 64];
        const unsigned int v13 = H[(size_t)s13 * 64];
        const unsigned int v14 = H[(size_t)s14 * 64];
        const unsigned int v15 = H[(size_t)s15 * 64];
        const float w1  = (e + 1  < e1) ? 1.f : 0.f;
        const float w2  = (e + 2  < e1) ? 1.f : 0.f;
        const float w3  = (e + 3  < e1) ? 1.f : 0.f;
        const float w4  = (e + 4  < e1) ? 1.f : 0.f;
        const float w5  = (e + 5  < e1) ? 1.f : 0.f;
        const float w6  = (e + 6  < e1) ? 1.f : 0.f;
        const float w7  = (e + 7  < e1) ? 1.f : 0.f;
        const float w8  = (e + 8  < e1) ? 1.f : 0.f;
        const float w9  = (e + 9  < e1) ? 1.f : 0.f;
        const float w10 = (e + 10 < e1) ? 1.f : 0.f;
        const float w11 = (e + 11 < e1) ? 1.f : 0.f;
        const float w12 = (e + 12 < e1) ? 1.f : 0.f;
        const float w13 = (e + 13 < e1) ? 1.f : 0.f;
        const float w14 = (e + 14 < e1) ? 1.f : 0.f;
        const float w15 = (e + 15 < e1) ? 1.f : 0.f;
        // elem 2*lane in low half, 2*lane+1 in high half
        a0 += __uint_as_float(v0 << 16);
        a1 += __uint_as_float(v0 & 0xFFFF0000u);
        a0 = fmaf(__uint_as_float(v1  << 16), w1,  a0);  a1 = fmaf(__uint_as_float(v1  & 0xFFFF0000u), w1,  a1);
        a0 = fmaf(__uint_as_float(v2  << 16), w2,  a0);  a1 = fmaf(__uint_as_float(v2  & 0xFFFF0000u), w2,  a1);
        a0 = fmaf(__uint_as_float(v3  << 16), w3,  a0);  a1 = fmaf(__uint_as_float(v3  & 0xFFFF0000u), w3,  a1);
        a0 = fmaf(__uint_as_float(v4  << 16), w4,  a0);  a1 = fmaf(__uint_as_float(v4  & 0xFFFF0000u), w4,  a1);
        a0 = fmaf(__uint_as_float(v5  << 16), w5,  a0);  a1 = fmaf(__uint_as_float(v5  & 0xFFFF0000u), w5,  a1);
        a0 = fmaf(__uint_as_float(v6  << 16), w6,  a0);  a1 = fmaf(__uint_as_float(v6  & 0xFFFF0000u), w6,  a1);
        a0 = fmaf(__uint_as_float(v7  << 16), w7,  a0);  a1 = fmaf(__uint_as_float(v7  & 0xFFFF0000u), w7,  a1);
        a0 = fmaf(__uint_as_float(v8  << 16), w8,  a0);  a1 = fmaf(__uint_as_float(v8  & 0xFFFF0000u), w8,  a1);
        a0 = fmaf(__uint_as_float(v9  << 16), w9,  a0);  a1 = fmaf(__uint_as_float(v9  & 0xFFFF0000u), w9,  a1);
        a0 = fmaf(__uint_as_float(v10 << 16), w10, a0);  a1 = fmaf(__uint_as_float(v10 & 0xFFFF0000u), w10, a1);
        a0 = fmaf(__uint_as_float(v11 << 16), w11, a0);  a1 = fmaf(__uint_as_float(v11 & 0xFFFF0000u), w11, a1);
        a0 = fmaf(__uint_as_float(v12 << 16), w12, a0);  a1 = fmaf(__uint_as_float(v12 & 0xFFFF0000u), w12, a1);
        a0 = fmaf(__uint_as_float(v13 << 16), w13, a0);  a1 = fmaf(__uint_as_float(v13 & 0xFFFF0000u), w13, a1);
        a0 = fmaf(__uint_as_float(v14 << 16), w14, a0);  a1 = fmaf(__uint_as_float(v14 & 0xFFFF0000u), w14, a1);
        a0 = fmaf(__uint_as_float(v15 << 16), w15, a0);  a1 = fmaf(__uint_as_float(v15 & 0xFFFF0000u), w15, a1);
    }
    const float inv = 1.f / (float)max(e1 - e0, 1);
    const unsigned int w = bfround(a0 * inv) | (bfround(a1 * inv) << 16);
    ((unsigned int*)Mb)[(size_t)n * 64 + lane] = w;
}

// ---------------- MFMA GEMM + LN + ReLU + residual ----------------
// A: mean = bf16 only (tiles 0-3, 2 MFMA terms), h = hi+lo packed
// (tiles 4-7, 3 terms) -> 160 MFMAs. K staged in 4 fully-unrolled
// quarters; linear fragment-order LDS (conflict-free, static offsets).

template<int MODE>
__global__ __launch_bounds__(256, 4)
void gemm_kernel(unsigned int* __restrict__ Apk,
                 unsigned short* __restrict__ Hh,
                 const unsigned short* __restrict__ Mb,
                 float* __restrict__ outF,
                 const unsigned short* __restrict__ Whi,
                 const unsigned short* __restrict__ Wlo,
                 const float* __restrict__ bl,
                 const float* __restrict__ gamma,
                 const float* __restrict__ beta) {
    // [hi/lo][tile = local kt pair][slot = rl*4+kg][8 ushort] : 32 KB
    __shared__ unsigned short Bs[2][16][64][8];

    const int tid  = threadIdx.x;
    const int lane = tid & 63;
    const int wave = tid >> 6;
    const int mt0  = blockIdx.x * 4 + wave;
    const int mt   = min(mt0, MTILES - 1);       // clamp; stores masked below
    const int rl   = lane & 15;
    const int kg   = lane >> 4;
    const int n    = mt * 16 + rl;
    const int slot = rl * 4 + kg;

    // ---- A fragments ----
    bf16x8 AM[4];                                 // mean, bf16 only
    {
        const unsigned int* __restrict__ mr =
            (const unsigned int*)Mb + (size_t)n * 64 + kg * 4;
        #pragma unroll
        for (int kt = 0; kt < 4; ++kt) {
            u32x4 m = *reinterpret_cast<const u32x4*>(mr + kt * 16);
            asm volatile("" : "+v"(m));
            AM[kt] = __builtin_bit_cast(bf16x8, m);
        }
    }
    bf16x8 AH[4], AL[4];                          // h, hi+lo
    {
        const unsigned int* __restrict__ ar = Apk + (size_t)n * 128 + kg * 8;
        #pragma unroll
        for (int kt = 0; kt < 4; ++kt) {
            const u32x4 p = *reinterpret_cast<const u32x4*>(ar + kt * 32);
            const u32x4 q = *reinterpret_cast<const u32x4*>(ar + kt * 32 + 4);
            u32x4 hw, lw;
            hw.x = (p.y & 0xFFFF0000u) | (p.x >> 16);
            hw.y = (p.w & 0xFFFF0000u) | (p.z >> 16);
            hw.z = (q.y & 0xFFFF0000u) | (q.x >> 16);
            hw.w = (q.w & 0xFFFF0000u) | (q.z >> 16);
            lw.x = (p.x & 0xFFFFu) | (p.y << 16);
            lw.y = (p.z & 0xFFFFu) | (p.w << 16);
            lw.z = (q.x & 0xFFFFu) | (q.y << 16);
            lw.w = (q.z & 0xFFFFu) | (q.w << 16);
            asm volatile("" : "+v"(hw), "+v"(lw));   // forbid remat
            AH[kt] = __builtin_bit_cast(bf16x8, hw);
            AL[kt] = __builtin_bit_cast(bf16x8, lw);
        }
    }

    f32x4 AC[8];
    #pragma unroll
    for (int jt = 0; jt < 8; ++jt) { AC[jt].x = 0.f; AC[jt].y = 0.f; AC[jt].z = 0.f; AC[jt].w = 0.f; }

    #pragma unroll
    for (int qu = 0; qu < 4; ++qu) {
        if (qu) __syncthreads();

        #pragma unroll
        for (int q = 0; q < 4; ++q) {
            const int c  = q * 256 + tid;        // 0..1023
            const int j  = c >> 3;               // row 0..127
            const int G  = c & 7;                // 16B granule within quarter
            const size_t gsrc = (size_t)j * 256 + qu * 64 + G * 8;
            const short8 vh = *reinterpret_cast<const short8*>(Whi + gsrc);
            const short8 vl = *reinterpret_cast<const short8*>(Wlo + gsrc);
            const int tile = (j >> 4) * 2 + (G >> 2);
            const int slw  = (j & 15) * 4 + (G & 3);
            *reinterpret_cast<short8*>(&Bs[0][tile][slw][0]) = vh;
            *reinterpret_cast<short8*>(&Bs[1][tile][slw][0]) = vl;
        }
        __syncthreads();

        #pragma unroll
        for (int jt = 0; jt < 8; ++jt) {
            #pragma unroll
            for (int ktl = 0; ktl < 2; ++ktl) {
                const bf16x8 BH = __builtin_bit_cast(bf16x8,
                    *reinterpret_cast<const short8*>(&Bs[0][jt * 2 + ktl][slot][0]));
                const bf16x8 BL = __builtin_bit_cast(bf16x8,
                    *reinterpret_cast<const short8*>(&Bs[1][jt * 2 + ktl][slot][0]));
                const int ka = qu * 2 + ktl;     // compile-time after unroll
                if (ka < 4) {                    // mean half: bf16 A
                    AC[jt] = __builtin_amdgcn_mfma_f32_16x16x32_bf16(AM[ka], BH, AC[jt], 0, 0, 0);
                    AC[jt] = __builtin_amdgcn_mfma_f32_16x16x32_bf16(AM[ka], BL, AC[jt], 0, 0, 0);
                } else {                         // h half: hi+lo A
                    AC[jt] = __builtin_amdgcn_mfma_f32_16x16x32_bf16(AH[ka - 4], BH, AC[jt], 0, 0, 0);
                    AC[jt] = __builtin_amdgcn_mfma_f32_16x16x32_bf16(AL[ka - 4], BH, AC[jt], 0, 0, 0);
                    AC[jt] = __builtin_amdgcn_mfma_f32_16x16x32_bf16(AH[ka - 4], BL, AC[jt], 0, 0, 0);
                }
            }
        }
    }

    // ---- bias ----
    #pragma unroll
    for (int jt = 0; jt < 8; ++jt) {
        const float bb = bl[jt * 16 + rl];
        AC[jt].x += bb; AC[jt].y += bb; AC[jt].z += bb; AC[jt].w += bb;
    }

    // ---- LayerNorm stats ----
    float mu[4], rs[4];
    #pragma unroll
    for (int r = 0; r < 4; ++r) {
        float s1 = 0.f, s2 = 0.f;
        #pragma unroll
        for (int jt = 0; jt < 8; ++jt) {
            const float v = AC[jt][r];
            s1 += v;
            s2 = fmaf(v, v, s2);
        }
        #pragma unroll
        for (int m = 1; m < 16; m <<= 1) {
            s1 += __shfl_xor(s1, m);
            s2 += __shfl_xor(s2, m);
        }
        mu[r] = s1 * (1.f / 128.f);
        const float var = fmaf(s2, 1.f / 128.f, -mu[r] * mu[r]);
        rs[r] = 1.f / sqrtf(var + EPS);
    }

    // ---- LN + ReLU + residual + store ----
    if (mt0 < MTILES) {
        #pragma unroll
        for (int jt = 0; jt < 8; ++jt) {
            const int j = jt * 16 + rl;
            const float g  = gamma[j];
            const float be = beta[j];
            #pragma unroll
            for (int r = 0; r < 4; ++r) {
                const int row = mt * 16 + kg * 4 + r;
                unsigned int* hp = Apk + (size_t)row * 128 + j;
                const float res = unpackbf(*hp);
                const float v = fmaxf(fmaf((AC[jt][r] - mu[r]) * rs[r], g, be), 0.f);
                const float o = res + v;
                if (MODE == 0) {
                    const unsigned int pk = packbf(o);
                    *hp = pk;
                    Hh[(size_t)row * D + j] = (unsigned short)(pk >> 16);
                } else {
                    outF[(size_t)row * D + j] = o;
                }
            }
        }
    }
}

// ---------------- launch ----------------

extern "C" void kernel_launch(void* const* d_in, const int* in_sizes, int n_in,
                              void* d_out, int out_size, void* d_ws, size_t ws_size,
                              hipStream_t stream) {
    const float* nf = (const float*)d_in[0];
    const int*   ei = (const int*)d_in[1];        // [2][E]: src row, dst row
    const float* Wl = (const float*)d_in[2];      // [3][128][128]
    const float* bl = (const float*)d_in[3];      // [3][128]
    const float* Wr = (const float*)d_in[4];
    const float* gm = (const float*)d_in[5];
    const float* bt = (const float*)d_in[6];
    float* out = (float*)d_out;

    char* w = (char*)d_ws;
    size_t off = 0;
    auto carve = [&](size_t bytes) -> char* {
        char* p = w + off;
        off = (off + bytes + 511) & ~(size_t)511;
        return p;
    };
    int*   deg       = (int*)carve((size_t)N_NODES * 4);
    int*   row_start = (int*)carve((size_t)(N_NODES + 1) * 4);
    int*   cursor    = (int*)carve((size_t)N_NODES * 4);
    int*   bsum      = (int*)carve((size_t)SCAN_B * 4);
    int*   bbase     = (int*)carve((size_t)SCAN_B * 4);
    int*   ssrc      = (int*)carve((size_t)N_EDGES * 4);
    unsigned int*   Apk = (unsigned int*)carve((size_t)N_NODES * 128 * 4);   // 25.6 MB packed h
    unsigned short* Hh  = (unsigned short*)carve((size_t)N_NODES * 128 * 2); // 12.8 MB bf16 h
    unsigned short* Mb  = (unsigned short*)carve((size_t)N_NODES * 128 * 2); // 12.8 MB bf16 mean
    unsigned short* Whi = (unsigned short*)carve((size_t)3 * 128 * 256 * 2);
    unsigned short* Wlo = (unsigned short*)carve((size_t)3 * 128 * 256 * 2);

    const int* src = ei;
    const int* dst = ei + N_EDGES;

    hipMemsetAsync(deg, 0, (size_t)N_NODES * 4, stream);
    count_kernel<<<(N_EDGES + 255) / 256, 256, 0, stream>>>(dst, deg);
    block_reduce_kernel<<<SCAN_B, 256, 0, stream>>>(deg, bsum);
    block_scan_kernel<<<1, 256, 0, stream>>>(bsum, bbase);
    expand_kernel<<<SCAN_B, 256, 0, stream>>>(deg, bbase, row_start, cursor);
    fill_kernel<<<(N_EDGES + 255) / 256, 256, 0, stream>>>(src, dst, cursor, ssrc);

    wprep_kernel<<<(3 * 128 * 256 + 255) / 256, 256, 0, stream>>>(Wl, Wr, Whi, Wlo);
    cvt0_kernel<<<(N_NODES * 32 + 255) / 256, 256, 0, stream>>>(nf, Apk, Hh);

    const int GA = (N_NODES + 3) / 4;        // 12500
    const int GG = (MTILES + 3) / 4;         // 782

    // layer 0
    agg_kernel<<<GA, THREADS, 0, stream>>>(Hh, Mb, row_start, ssrc);
    gemm_kernel<0><<<GG, THREADS, 0, stream>>>(Apk, Hh, Mb, nullptr, Whi, Wlo, bl, gm, bt);
    // layer 1
    agg_kernel<<<GA, THREADS, 0, stream>>>(Hh, Mb, row_start, ssrc);
    gemm_kernel<0><<<GG, THREADS, 0, stream>>>(Apk, Hh, Mb, nullptr,
                                               Whi + 32768, Wlo + 32768,
                                               bl + D, gm + D, bt + D);
    // layer 2
    agg_kernel<<<GA, THREADS, 0, stream>>>(Hh, Mb, row_start, ssrc);
    gemm_kernel<1><<<GG, THREADS, 0, stream>>>(Apk, Hh, Mb, out,
                                               Whi + 65536, Wlo + 65536,
                                               bl + 2 * D, gm + 2 * D, bt + 2 * D);
}

// Round 9
// 300.063 us; speedup vs baseline: 5.3140x; 1.2194x over previous
//
#include <hip/hip_runtime.h>

#define N_NODES 50000
#define N_EDGES 800000
#define D       128
#define THREADS 256
#define EPS     1e-5f
#define MTILES  3125    // N_NODES / 16
#define NBINS   391     // ceil(N_NODES / 128), bin = dst >> 7
#define BINCAP  4096    // edges per bin capacity (avg ~2046, Poisson tail ~0)
#define SCAT_B  196     // binscatter blocks
#define EPB     4096    // edges per binscatter block

typedef __attribute__((ext_vector_type(8))) __bf16  bf16x8;
typedef __attribute__((ext_vector_type(8))) short   short8;
typedef __attribute__((ext_vector_type(4))) float   f32x4;
typedef __attribute__((ext_vector_type(4))) unsigned int u32x4;

// fp32 -> bf16 (rne), as low 16 bits
__device__ inline unsigned int bfround(float x) {
    unsigned int u = __float_as_uint(x);
    return (u + 0x7FFFu + ((u >> 16) & 1u)) >> 16;
}
// pack fp32 -> (bf16_hi << 16) | bf16_lo   (hi+lo ~= x to ~2^-17 rel)
__device__ inline unsigned int packbf(float x) {
    unsigned int hi = bfround(x);
    float lo = x - __uint_as_float(hi << 16);
    return (hi << 16) | (bfround(lo) & 0xFFFFu);
}
__device__ inline float unpackbf(unsigned int u) {
    return __uint_as_float(u & 0xFFFF0000u) + __uint_as_float(u << 16);
}

// ---------------- binned CSR build (no random 4B scatter) ----------------

// blocks of 4096 edges: LDS histogram over 391 bins -> one global atomic per
// (block,bin) -> burst-write (src,dst) pairs into bin segments.
__global__ __launch_bounds__(THREADS)
void binscatter_kernel(const int* __restrict__ src, const int* __restrict__ dst,
                       int* __restrict__ bincnt, uint2* __restrict__ binbuf) {
    __shared__ int hist[NBINS];
    __shared__ int base[NBINS];
    const int tid = threadIdx.x;
    for (int t = tid; t < NBINS; t += THREADS) hist[t] = 0;
    __syncthreads();
    const int e0 = blockIdx.x * EPB;
    #pragma unroll 1
    for (int r = 0; r < EPB / THREADS; ++r) {
        const int e = e0 + r * THREADS + tid;
        if (e < N_EDGES) atomicAdd(&hist[dst[e] >> 7], 1);
    }
    __syncthreads();
    for (int t = tid; t < NBINS; t += THREADS) {
        const int h = hist[t];
        base[t] = h ? atomicAdd(&bincnt[t], h) : 0;
        hist[t] = 0;                       // reuse as per-bin cursor
    }
    __syncthreads();
    #pragma unroll 1
    for (int r = 0; r < EPB / THREADS; ++r) {
        const int e = e0 + r * THREADS + tid;
        if (e < N_EDGES) {
            const int d = dst[e];
            const int b = d >> 7;
            const int p = base[b] + atomicAdd(&hist[b], 1);
            if (p < BINCAP)
                binbuf[(size_t)b * BINCAP + p] = make_uint2((unsigned)src[e], (unsigned)d);
        }
    }
}

__global__ __launch_bounds__(512)
void binscan_kernel(const int* __restrict__ bincnt, int* __restrict__ binbase,
                    int* __restrict__ row_start) {
    __shared__ int s[512];
    const int t = threadIdx.x;
    const int v = (t < NBINS) ? bincnt[t] : 0;
    s[t] = v;
    __syncthreads();
    for (int off = 1; off < 512; off <<= 1) {
        const int a = (t >= off) ? s[t - off] : 0;
        __syncthreads();
        s[t] += a;
        __syncthreads();
    }
    if (t < NBINS) binbase[t] = s[t] - v;  // exclusive
    if (t == 0) row_start[N_NODES] = N_EDGES;
}

// one block per bin: LDS-cached edges -> per-node count/scan/scatter in LDS,
// coalesced single-owner writes of row_start and ssrc (no line bouncing).
__global__ __launch_bounds__(THREADS)
void csrbin_kernel(const int* __restrict__ bincnt, const int* __restrict__ binbase,
                   const uint2* __restrict__ binbuf,
                   int* __restrict__ row_start, int* __restrict__ ssrc) {
    __shared__ uint2 ec[BINCAP];           // 32 KB
    __shared__ int cnt[128], exc[128], cur[128];
    const int tid = threadIdx.x;
    const int b   = blockIdx.x;
    const int nb  = min(bincnt[b], BINCAP);
    const int gb  = binbase[b];
    if (tid < 128) { cnt[tid] = 0; cur[tid] = 0; }
    __syncthreads();
    #pragma unroll 1
    for (int i = tid; i < nb; i += THREADS) {
        const uint2 e = binbuf[(size_t)b * BINCAP + i];
        ec[i] = e;
        atomicAdd(&cnt[e.y & 127], 1);
    }
    __syncthreads();
    if (tid < 128) exc[tid] = cnt[tid];
    __syncthreads();
    for (int off = 1; off < 128; off <<= 1) {
        const int a = (tid < 128 && tid >= off) ? exc[tid - off] : 0;
        __syncthreads();
        if (tid < 128) exc[tid] += a;      // inclusive scan
        __syncthreads();
    }
    if (tid < 128) {
        const int n = b * 128 + tid;
        if (n < N_NODES) row_start[n] = gb + exc[tid] - cnt[tid];
    }
    __syncthreads();
    #pragma unroll 1
    for (int i = tid; i < nb; i += THREADS) {
        const uint2 e = ec[i];
        const int nl = e.y & 127;
        const int p  = atomicAdd(&cur[nl], 1);
        ssrc[gb + exc[nl] - cnt[nl] + p] = (int)e.x;
    }
}

// ---------------- prep ----------------

// Whi/Wlo: [3][128][256] ushort, row j = concat(Wl[j][:], Wr[j][:])
__global__ void wprep_kernel(const float* __restrict__ Wl, const float* __restrict__ Wr,
                             unsigned short* __restrict__ Whi, unsigned short* __restrict__ Wlo) {
    int t = blockIdx.x * 256 + threadIdx.x;
    if (t >= 3 * 128 * 256) return;
    const int L = t >> 15;
    const int r = t & 32767;
    const int j = r >> 8;
    const int k = r & 255;
    const float x = (k < 128) ? Wl[((size_t)L * 128 + j) * 128 + k]
                              : Wr[((size_t)L * 128 + j) * 128 + (k - 128)];
    const unsigned int p = packbf(x);
    Whi[t] = (unsigned short)(p >> 16);
    Wlo[t] = (unsigned short)(p & 0xFFFFu);
}

// layer-0: fp32 node_features -> packed Apk [n][128] and bf16 Hh [n][128]
__global__ void cvt0_kernel(const float* __restrict__ nf,
                            unsigned int* __restrict__ Apk,
                            unsigned short* __restrict__ Hh) {
    int t = blockIdx.x * 256 + threadIdx.x;   // one thread per 4 elems
    if (t >= N_NODES * 32) return;
    const int n  = t >> 5;
    const int k4 = (t & 31) * 4;
    const float4 v = *reinterpret_cast<const float4*>(nf + (size_t)n * D + k4);
    u32x4 o;
    o.x = packbf(v.x); o.y = packbf(v.y); o.z = packbf(v.z); o.w = packbf(v.w);
    *reinterpret_cast<u32x4*>(Apk + (size_t)n * 128 + k4) = o;
    uint2 hh;
    hh.x = (o.x >> 16) | (o.y & 0xFFFF0000u);
    hh.y = (o.z >> 16) | (o.w & 0xFFFF0000u);
    *reinterpret_cast<uint2*>((unsigned int*)Hh + (size_t)n * 64 + (k4 >> 1)) = hh;
}

// ---------------- aggregation: Mb[n][128] bf16 = mean of Hh[src] ----------------
// Wave-per-node; 256B bf16 rows (1 dword/lane); 16-deep clamped+weighted
// load pipeline; scalar edge indices.

__global__ __launch_bounds__(256, 8)
void agg_kernel(const unsigned short* __restrict__ Hh,
                unsigned short* __restrict__ Mb,
                const int* __restrict__ row_start, const int* __restrict__ ssrc) {
    const int lane = threadIdx.x & 63;
    const int wave = threadIdx.x >> 6;
    const int n = blockIdx.x * 4 + wave;
    if (n >= N_NODES) return;
    const int e0 = __builtin_amdgcn_readfirstlane(row_start[n]);
    const int e1 = __builtin_amdgcn_readfirstlane(row_start[n + 1]);
    const unsigned int* __restrict__ H = (const unsigned int*)Hh + lane;  // +64/row

    float a0 = 0.f, a1 = 0.f;
    #pragma unroll 1
    for (int e = e0; e < e1; e += 16) {
        const int el = e1 - 1;
        const int s0  = ssrc[min(e + 0,  el)];
        const int s1  = ssrc[min(e + 1,  el)];
        const int s2  = ssrc[min(e + 2,  el)];
        const int s3  = ssrc[min(e + 3,  el)];
        const int s4  = ssrc[min(e + 4,  el)];
        const int s5  = ssrc[min(e + 5,  el)];
        const int s6  = ssrc[min(e + 6,  el)];
        const int s7  = ssrc[min(e + 7,  el)];
        const int s8  = ssrc[min(e + 8,  el)];
        const int s9  = ssrc[min(e + 9,  el)];
        const int s10 = ssrc[min(e + 10, el)];
        const int s11 = ssrc[min(e + 11, el)];
        const int s12 = ssrc[min(e + 12, el)];
        const int s13 = ssrc[min(e + 13, el)];
        const int s14 = ssrc[min(e + 14, el)];
        const int s15 = ssrc[min(e + 15, el)];
        const unsigned int v0  = H[(size_t)s0  * 64];
        const unsigned int v1  = H[(size_t)s1  * 64];
        const unsigned int v2  = H[(size_t)s2  * 64];
        const unsigned int v3  = H[(size_t)s3  * 64];
        const unsigned int v4  = H[(size_t)s4  * 64];
        const unsigned int v5  = H[(size_t)s5  * 64];
        const unsigned int v6  = H[(size_t)s6  * 64];
        const unsigned int v7  = H[(size_t)s7  * 64];
        const unsigned int v8  = H[(size_t)s8  * 64];
        const unsigned int v9  = H[(size_t)s9  * 64];
        const unsigned int v10 = H[(size_t)s10 * 64];
        const unsigned int v11 = H[(size_t)s11 * 64];
        const unsigned int v12 = H[(size_t)s12 * 64];
        const unsigned int v13 = H[(size_t)s13 * 64];
        const unsigned int v14 = H[(size_t)s14 * 64];
        const unsigned int v15 = H[(size_t)s15 * 64];
        const float w1  = (e + 1  < e1) ? 1.f : 0.f;
        const float w2  = (e + 2  < e1) ? 1.f : 0.f;
        const float w3  = (e + 3  < e1) ? 1.f : 0.f;
        const float w4  = (e + 4  < e1) ? 1.f : 0.f;
        const float w5  = (e + 5  < e1) ? 1.f : 0.f;
        const float w6  = (e + 6  < e1) ? 1.f : 0.f;
        const float w7  = (e + 7  < e1) ? 1.f : 0.f;
        const float w8  = (e + 8  < e1) ? 1.f : 0.f;
        const float w9  = (e + 9  < e1) ? 1.f : 0.f;
        const float w10 = (e + 10 < e1) ? 1.f : 0.f;
        const float w11 = (e + 11 < e1) ? 1.f : 0.f;
        const float w12 = (e + 12 < e1) ? 1.f : 0.f;
        const float w13 = (e + 13 < e1) ? 1.f : 0.f;
        const float w14 = (e + 14 < e1) ? 1.f : 0.f;
        const float w15 = (e + 15 < e1) ? 1.f : 0.f;
        a0 += __uint_as_float(v0 << 16);
        a1 += __uint_as_float(v0 & 0xFFFF0000u);
        a0 = fmaf(__uint_as_float(v1  << 16), w1,  a0);  a1 = fmaf(__uint_as_float(v1  & 0xFFFF0000u), w1,  a1);
        a0 = fmaf(__uint_as_float(v2  << 16), w2,  a0);  a1 = fmaf(__uint_as_float(v2  & 0xFFFF0000u), w2,  a1);
        a0 = fmaf(__uint_as_float(v3  << 16), w3,  a0);  a1 = fmaf(__uint_as_float(v3  & 0xFFFF0000u), w3,  a1);
        a0 = fmaf(__uint_as_float(v4  << 16), w4,  a0);  a1 = fmaf(__uint_as_float(v4  & 0xFFFF0000u), w4,  a1);
        a0 = fmaf(__uint_as_float(v5  << 16), w5,  a0);  a1 = fmaf(__uint_as_float(v5  & 0xFFFF0000u), w5,  a1);
        a0 = fmaf(__uint_as_float(v6  << 16), w6,  a0);  a1 = fmaf(__uint_as_float(v6  & 0xFFFF0000u), w6,  a1);
        a0 = fmaf(__uint_as_float(v7  << 16), w7,  a0);  a1 = fmaf(__uint_as_float(v7  & 0xFFFF0000u), w7,  a1);
        a0 = fmaf(__uint_as_float(v8  << 16), w8,  a0);  a1 = fmaf(__uint_as_float(v8  & 0xFFFF0000u), w8,  a1);
        a0 = fmaf(__uint_as_float(v9  << 16), w9,  a0);  a1 = fmaf(__uint_as_float(v9  & 0xFFFF0000u), w9,  a1);
        a0 = fmaf(__uint_as_float(v10 << 16), w10, a0);  a1 = fmaf(__uint_as_float(v10 & 0xFFFF0000u), w10, a1);
        a0 = fmaf(__uint_as_float(v11 << 16), w11, a0);  a1 = fmaf(__uint_as_float(v11 & 0xFFFF0000u), w11, a1);
        a0 = fmaf(__uint_as_float(v12 << 16), w12, a0);  a1 = fmaf(__uint_as_float(v12 & 0xFFFF0000u), w12, a1);
        a0 = fmaf(__uint_as_float(v13 << 16), w13, a0);  a1 = fmaf(__uint_as_float(v13 & 0xFFFF0000u), w13, a1);
        a0 = fmaf(__uint_as_float(v14 << 16), w14, a0);  a1 = fmaf(__uint_as_float(v14 & 0xFFFF0000u), w14, a1);
        a0 = fmaf(__uint_as_float(v15 << 16), w15, a0);  a1 = fmaf(__uint_as_float(v15 & 0xFFFF0000u), w15, a1);
    }
    const float inv = 1.f / (float)max(e1 - e0, 1);
    const unsigned int w = bfround(a0 * inv) | (bfround(a1 * inv) << 16);
    ((unsigned int*)Mb)[(size_t)n * 64 + lane] = w;
}

// ---------------- MFMA GEMM + LN + ReLU + residual ----------------
// A: mean = bf16 only (tiles 0-3, 2 MFMA terms), h = hi+lo packed
// (tiles 4-7, 3 terms) -> 160 MFMAs. K staged in 4 fully-unrolled
// quarters; linear fragment-order LDS (conflict-free, static offsets).

template<int MODE>
__global__ __launch_bounds__(256, 4)
void gemm_kernel(unsigned int* __restrict__ Apk,
                 unsigned short* __restrict__ Hh,
                 const unsigned short* __restrict__ Mb,
                 float* __restrict__ outF,
                 const unsigned short* __restrict__ Whi,
                 const unsigned short* __restrict__ Wlo,
                 const float* __restrict__ bl,
                 const float* __restrict__ gamma,
                 const float* __restrict__ beta) {
    // [hi/lo][tile = local kt pair][slot = rl*4+kg][8 ushort] : 32 KB
    __shared__ unsigned short Bs[2][16][64][8];

    const int tid  = threadIdx.x;
    const int lane = tid & 63;
    const int wave = tid >> 6;
    const int mt0  = blockIdx.x * 4 + wave;
    const int mt   = min(mt0, MTILES - 1);       // clamp; stores masked below
    const int rl   = lane & 15;
    const int kg   = lane >> 4;
    const int n    = mt * 16 + rl;
    const int slot = rl * 4 + kg;

    // ---- A fragments ----
    bf16x8 AM[4];                                 // mean, bf16 only
    {
        const unsigned int* __restrict__ mr =
            (const unsigned int*)Mb + (size_t)n * 64 + kg * 4;
        #pragma unroll
        for (int kt = 0; kt < 4; ++kt) {
            u32x4 m = *reinterpret_cast<const u32x4*>(mr + kt * 16);
            asm volatile("" : "+v"(m));
            AM[kt] = __builtin_bit_cast(bf16x8, m);
        }
    }
    bf16x8 AH[4], AL[4];                          // h, hi+lo
    {
        const unsigned int* __restrict__ ar = Apk + (size_t)n * 128 + kg * 8;
        #pragma unroll
        for (int kt = 0; kt < 4; ++kt) {
            const u32x4 p = *reinterpret_cast<const u32x4*>(ar + kt * 32);
            const u32x4 q = *reinterpret_cast<const u32x4*>(ar + kt * 32 + 4);
            u32x4 hw, lw;
            hw.x = (p.y & 0xFFFF0000u) | (p.x >> 16);
            hw.y = (p.w & 0xFFFF0000u) | (p.z >> 16);
            hw.z = (q.y & 0xFFFF0000u) | (q.x >> 16);
            hw.w = (q.w & 0xFFFF0000u) | (q.z >> 16);
            lw.x = (p.x & 0xFFFFu) | (p.y << 16);
            lw.y = (p.z & 0xFFFFu) | (p.w << 16);
            lw.z = (q.x & 0xFFFFu) | (q.y << 16);
            lw.w = (q.z & 0xFFFFu) | (q.w << 16);
            asm volatile("" : "+v"(hw), "+v"(lw));   // forbid remat
            AH[kt] = __builtin_bit_cast(bf16x8, hw);
            AL[kt] = __builtin_bit_cast(bf16x8, lw);
        }
    }

    f32x4 AC[8];
    #pragma unroll
    for (int jt = 0; jt < 8; ++jt) { AC[jt].x = 0.f; AC[jt].y = 0.f; AC[jt].z = 0.f; AC[jt].w = 0.f; }

    #pragma unroll
    for (int qu = 0; qu < 4; ++qu) {
        if (qu) __syncthreads();

        #pragma unroll
        for (int q = 0; q < 4; ++q) {
            const int c  = q * 256 + tid;        // 0..1023
            const int j  = c >> 3;               // row 0..127
            const int G  = c & 7;                // 16B granule within quarter
            const size_t gsrc = (size_t)j * 256 + qu * 64 + G * 8;
            const short8 vh = *reinterpret_cast<const short8*>(Whi + gsrc);
            const short8 vl = *reinterpret_cast<const short8*>(Wlo + gsrc);
            const int tile = (j >> 4) * 2 + (G >> 2);
            const int slw  = (j & 15) * 4 + (G & 3);
            *reinterpret_cast<short8*>(&Bs[0][tile][slw][0]) = vh;
            *reinterpret_cast<short8*>(&Bs[1][tile][slw][0]) = vl;
        }
        __syncthreads();

        #pragma unroll
        for (int jt = 0; jt < 8; ++jt) {
            #pragma unroll
            for (int ktl = 0; ktl < 2; ++ktl) {
                const bf16x8 BH = __builtin_bit_cast(bf16x8,
                    *reinterpret_cast<const short8*>(&Bs[0][jt * 2 + ktl][slot][0]));
                const bf16x8 BL = __builtin_bit_cast(bf16x8,
                    *reinterpret_cast<const short8*>(&Bs[1][jt * 2 + ktl][slot][0]));
                const int ka = qu * 2 + ktl;     // compile-time after unroll
                if (ka < 4) {                    // mean half: bf16 A
                    AC[jt] = __builtin_amdgcn_mfma_f32_16x16x32_bf16(AM[ka], BH, AC[jt], 0, 0, 0);
                    AC[jt] = __builtin_amdgcn_mfma_f32_16x16x32_bf16(AM[ka], BL, AC[jt], 0, 0, 0);
                } else {                         // h half: hi+lo A
                    AC[jt] = __builtin_amdgcn_mfma_f32_16x16x32_bf16(AH[ka - 4], BH, AC[jt], 0, 0, 0);
                    AC[jt] = __builtin_amdgcn_mfma_f32_16x16x32_bf16(AL[ka - 4], BH, AC[jt], 0, 0, 0);
                    AC[jt] = __builtin_amdgcn_mfma_f32_16x16x32_bf16(AH[ka - 4], BL, AC[jt], 0, 0, 0);
                }
            }
        }
    }

    // ---- bias ----
    #pragma unroll
    for (int jt = 0; jt < 8; ++jt) {
        const float bb = bl[jt * 16 + rl];
        AC[jt].x += bb; AC[jt].y += bb; AC[jt].z += bb; AC[jt].w += bb;
    }

    // ---- LayerNorm stats ----
    float mu[4], rs[4];
    #pragma unroll
    for (int r = 0; r < 4; ++r) {
        float s1 = 0.f, s2 = 0.f;
        #pragma unroll
        for (int jt = 0; jt < 8; ++jt) {
            const float v = AC[jt][r];
            s1 += v;
            s2 = fmaf(v, v, s2);
        }
        #pragma unroll
        for (int m = 1; m < 16; m <<= 1) {
            s1 += __shfl_xor(s1, m);
            s2 += __shfl_xor(s2, m);
        }
        mu[r] = s1 * (1.f / 128.f);
        const float var = fmaf(s2, 1.f / 128.f, -mu[r] * mu[r]);
        rs[r] = 1.f / sqrtf(var + EPS);
    }

    // ---- LN + ReLU + residual + store ----
    if (mt0 < MTILES) {
        #pragma unroll
        for (int jt = 0; jt < 8; ++jt) {
            const int j = jt * 16 + rl;
            const float g  = gamma[j];
            const float be = beta[j];
            #pragma unroll
            for (int r = 0; r < 4; ++r) {
                const int row = mt * 16 + kg * 4 + r;
                unsigned int* hp = Apk + (size_t)row * 128 + j;
                const float res = unpackbf(*hp);
                const float v = fmaxf(fmaf((AC[jt][r] - mu[r]) * rs[r], g, be), 0.f);
                const float o = res + v;
                if (MODE == 0) {
                    const unsigned int pk = packbf(o);
                    *hp = pk;
                    Hh[(size_t)row * D + j] = (unsigned short)(pk >> 16);
                } else {
                    outF[(size_t)row * D + j] = o;
                }
            }
        }
    }
}

// ---------------- launch ----------------

extern "C" void kernel_launch(void* const* d_in, const int* in_sizes, int n_in,
                              void* d_out, int out_size, void* d_ws, size_t ws_size,
                              hipStream_t stream) {
    const float* nf = (const float*)d_in[0];
    const int*   ei = (const int*)d_in[1];        // [2][E]: src row, dst row
    const float* Wl = (const float*)d_in[2];      // [3][128][128]
    const float* bl = (const float*)d_in[3];      // [3][128]
    const float* Wr = (const float*)d_in[4];
    const float* gm = (const float*)d_in[5];
    const float* bt = (const float*)d_in[6];
    float* out = (float*)d_out;

    char* w = (char*)d_ws;
    size_t off = 0;
    auto carve = [&](size_t bytes) -> char* {
        char* p = w + off;
        off = (off + bytes + 511) & ~(size_t)511;
        return p;
    };
    int*   bincnt    = (int*)carve((size_t)NBINS * 4);
    int*   binbase   = (int*)carve((size_t)NBINS * 4);
    int*   row_start = (int*)carve((size_t)(N_NODES + 1) * 4);
    int*   ssrc      = (int*)carve((size_t)N_EDGES * 4);
    uint2* binbuf    = (uint2*)carve((size_t)NBINS * BINCAP * 8);             // 12.8 MB
    unsigned int*   Apk = (unsigned int*)carve((size_t)N_NODES * 128 * 4);   // 25.6 MB packed h
    unsigned short* Hh  = (unsigned short*)carve((size_t)N_NODES * 128 * 2); // 12.8 MB bf16 h
    unsigned short* Mb  = (unsigned short*)carve((size_t)N_NODES * 128 * 2); // 12.8 MB bf16 mean
    unsigned short* Whi = (unsigned short*)carve((size_t)3 * 128 * 256 * 2);
    unsigned short* Wlo = (unsigned short*)carve((size_t)3 * 128 * 256 * 2);

    const int* src = ei;
    const int* dst = ei + N_EDGES;

    hipMemsetAsync(bincnt, 0, (size_t)NBINS * 4, stream);
    binscatter_kernel<<<SCAT_B, THREADS, 0, stream>>>(src, dst, bincnt, binbuf);
    binscan_kernel<<<1, 512, 0, stream>>>(bincnt, binbase, row_start);
    csrbin_kernel<<<NBINS, THREADS, 0, stream>>>(bincnt, binbase, binbuf, row_start, ssrc);

    wprep_kernel<<<(3 * 128 * 256 + 255) / 256, 256, 0, stream>>>(Wl, Wr, Whi, Wlo);
    cvt0_kernel<<<(N_NODES * 32 + 255) / 256, 256, 0, stream>>>(nf, Apk, Hh);

    const int GA = (N_NODES + 3) / 4;        // 12500
    const int GG = (MTILES + 3) / 4;         // 782

    // layer 0
    agg_kernel<<<GA, THREADS, 0, stream>>>(Hh, Mb, row_start, ssrc);
    gemm_kernel<0><<<GG, THREADS, 0, stream>>>(Apk, Hh, Mb, nullptr, Whi, Wlo, bl, gm, bt);
    // layer 1
    agg_kernel<<<GA, THREADS, 0, stream>>>(Hh, Mb, row_start, ssrc);
    gemm_kernel<0><<<GG, THREADS, 0, stream>>>(Apk, Hh, Mb, nullptr,
                                               Whi + 32768, Wlo + 32768,
                                               bl + D, gm + D, bt + D);
    // layer 2
    agg_kernel<<<GA, THREADS, 0, stream>>>(Hh, Mb, row_start, ssrc);
    gemm_kernel<1><<<GG, THREADS, 0, stream>>>(Apk, Hh, Mb, out,
                                               Whi + 65536, Wlo + 65536,
                                               bl + 2 * D, gm + 2 * D, bt + 2 * D);
}